// Round 4
// baseline (78.818 us; speedup 1.0000x reference)
//
#include <hip/hip_runtime.h>
#include <math.h>

// PeakSense: out[b,p] = sum_i exp(-0.5*(mz[b,i]-mu[p])^2 * exp(-lv[p])) * iv[b,i],
// terms with arg < -10 dropped.
//
// R4 = R1's measured-best structure (whole-row LDS stage issued early into
// registers, split binary search on GLOBAL overlapped with the in-flight
// staging loads, LDS writes late, one barrier) + three fixes from the R3
// post-mortem (no-LDS variant regressed 68.9->73.5: search had nothing to
// overlap with, main loop sat at L2 latency):
//  - SUB=8, 32 peaks/block, pgroups=8 -> 1024 blocks = 4 blocks/CU (2x TLP
//    vs R1), ~9 main-loop terms per lane.
//  - LDS de-interleaved into sm[]/si[] so staging ds_write_b128 is
//    lane-contiguous (16B/lane, conflict-free) -- R1's float2 interleave
//    made every b128 write an 8-way bank conflict (32B lane stride).
//  - mu/lv loads hoisted above the staging loads so the search's gate
//    values are in flight with them.
// Exact per-term threshold test kept -> same accumulation set as ref.

#define BLOCK 256
#define SUB 8
#define PPB (BLOCK / SUB)   // 32 peaks per block
#define MAXL 4096
#define THRESH -10.0f

__global__ __launch_bounds__(BLOCK) void peaksense_kernel(
    const float* __restrict__ mu,
    const float* __restrict__ lv,
    const float* __restrict__ masses,
    const float* __restrict__ inten,
    float* __restrict__ out,
    int B, int L, int N)
{
    __shared__ float sm[MAXL];   // masses, 16 KB
    __shared__ float si[MAXL];   // intensities, 16 KB

    const int pg = blockIdx.x;   // peak group
    const int b  = blockIdx.y;
    const int t  = threadIdx.x;

    // ---- hoisted peak-parameter loads (issue first, gate the search) ----
    const int  lp     = t >> 3;        // local peak 0..31
    const int  sub    = t & 7;         // eighth-range selector
    const int  p      = pg * PPB + lp;
    const bool active = (p < N);
    const int  pc     = active ? p : (N - 1);   // clamp for safe loads
    const float mu_p  = mu[pc];                 // 8 lanes broadcast-share
    const float lvp   = lv[pc];

    const float* __restrict__ mrow = masses + (size_t)b * L;
    const float* __restrict__ irow = inten  + (size_t)b * L;

    const bool fast = (L == MAXL);   // L=4096: statically unrolled staging

    // ---- phase 1: issue whole-row staging loads into registers, so the
    // global binary search below overlaps the in-flight loads ----
    float4 mv[4], vv[4];
    if (fast) {
        const float4* __restrict__ m4 = reinterpret_cast<const float4*>(mrow);
        const float4* __restrict__ i4 = reinterpret_cast<const float4*>(irow);
        #pragma unroll
        for (int k = 0; k < 4; ++k) {
            mv[k] = m4[t + k * BLOCK];
            vv[k] = i4[t + k * BLOCK];
        }
    }

    const float inv  = __expf(-lvp);           // 1/sigma^2
    const float nh   = -0.5f * inv;
    // arg >= -10  <=>  |d| <= sqrt(20)*sigma; margin covers fp rounding, the
    // exact per-term test below keeps the result bit-for-bit identical.
    const float r    = sqrtf(20.0f / inv) * 1.00001f + 1e-3f;
    const float tlo  = mu_p - r;
    const float thi  = mu_p + r;

    // ---- split binary search on the GLOBAL row (overlaps staging loads):
    // even subs: first i with m >= tlo; odd subs: first i with m > thi.
    // Exactly 12 uniform iterations for L=4096 -> no trip-count divergence.
    const bool  isHi   = sub & 1;
    const float target = isHi ? thi : tlo;
    int lo = 0, hi = L;
    while (lo < hi) {
        const int   mid = (lo + hi) >> 1;
        const float v   = mrow[mid];
        const bool  go  = isHi ? (v <= target) : (v < target);
        if (go) lo = mid + 1; else hi = mid;
    }
    const int other = __shfl_xor(lo, 1);
    const int start = isHi ? other : lo;
    const int end   = isHi ? lo    : other;

    // ---- phase 2: LDS writes (lane-contiguous b128, conflict-free) ----
    if (fast) {
        float4* __restrict__ smw = reinterpret_cast<float4*>(sm);
        float4* __restrict__ siw = reinterpret_cast<float4*>(si);
        #pragma unroll
        for (int k = 0; k < 4; ++k) {
            smw[t + k * BLOCK] = mv[k];
            siw[t + k * BLOCK] = vv[k];
        }
    } else {
        for (int i = t; i < L; i += BLOCK) {
            sm[i] = mrow[i];
            si[i] = irow[i];
        }
    }
    __syncthreads();               // only barrier; no thread returned above

    // ---- main loop: ~9 terms per lane from LDS ----
    float acc = 0.0f;
    for (int i = start + sub; i < end; i += SUB) {
        const float d   = sm[i] - mu_p;
        const float arg = d * d * nh;
        if (arg >= THRESH)
            acc += __expf(arg) * si[i];
    }
    acc += __shfl_xor(acc, 1);                 // merge the 8-lane group
    acc += __shfl_xor(acc, 2);
    acc += __shfl_xor(acc, 4);
    if (sub == 0 && active)
        out[(size_t)b * N + p] = acc;          // exactly-once '=' write
}

extern "C" void kernel_launch(void* const* d_in, const int* in_sizes, int n_in,
                              void* d_out, int out_size, void* d_ws, size_t ws_size,
                              hipStream_t stream) {
    const float* mu     = (const float*)d_in[0];
    const float* lv     = (const float*)d_in[1];
    const float* masses = (const float*)d_in[2];
    const float* inten  = (const float*)d_in[3];
    float* out = (float*)d_out;

    const int N = in_sizes[0];
    const int B = out_size / N;
    const int L = in_sizes[2] / B;

    const int pgroups = (N + PPB - 1) / PPB;   // 8 for N=256
    dim3 grid(pgroups, B);                     // 1024 blocks -> 4 per CU
    peaksense_kernel<<<grid, BLOCK, 0, stream>>>(mu, lv, masses, inten, out, B, L, N);
}

// Round 5
// 66.478 us; speedup vs baseline: 1.1856x; 1.1856x over previous
//
#include <hip/hip_runtime.h>
#include <math.h>

// PeakSense: out[b,p] = sum_i exp(-0.5*(mz[b,i]-mu[p])^2 * exp(-lv[p])) * iv[b,i],
// terms with arg < -10 dropped.
//
// R5: minimal-fetch discriminating probe (M1 "kernel improvable" vs M2
// "post-fill writeback-drain floor"). Evidence so far: dur_us vs kernel
// FETCH_SIZE = {8MB:70.0, 16MB:68.9, scattered:73.5, 33.6MB:78.8} -- volume
// insensitive below ~16MB, expensive above -> suspect the 256MiB harness
// fill's writeback tail congests HBM into the kernel's window.
// This kernel minimizes both fetch volume AND scattered reads:
//  - pgroups=2, BLOCK=512: 256 blocks (1/CU, 8 waves/CU), fetch = 8 MB
//    contiguous, no global-memory binary search at all.
//  - float4 issue-early staging (4 loads in flight), lane-contiguous
//    ds_write_b128, single barrier.
//  - split binary search IN LDS (even subs lower bound, odd subs upper,
//    12 uniform steps for L=4096, ~120cy each), shfl_xor(1) exchange.
//  - SUB=4 lanes/peak -> ~18 main-loop terms per lane from LDS.
// Exact per-term threshold test kept -> same accumulation set as ref.

#define BLOCK 512
#define SUB 4
#define PPB (BLOCK / SUB)   // 128 peaks per block
#define MAXL 4096
#define THRESH -10.0f

__global__ __launch_bounds__(BLOCK) void peaksense_kernel(
    const float* __restrict__ mu,
    const float* __restrict__ lv,
    const float* __restrict__ masses,
    const float* __restrict__ inten,
    float* __restrict__ out,
    int B, int L, int N)
{
    __shared__ float sm[MAXL];   // masses, 16 KB
    __shared__ float si[MAXL];   // intensities, 16 KB

    const int pg = blockIdx.x;   // peak group
    const int b  = blockIdx.y;
    const int t  = threadIdx.x;

    // ---- hoisted peak-parameter loads ----
    const int  lp     = t >> 2;        // local peak 0..127
    const int  sub    = t & 3;         // quarter-range selector
    const int  p      = pg * PPB + lp;
    const bool active = (p < N);
    const int  pc     = active ? p : (N - 1);   // clamp for safe loads
    const float mu_p  = mu[pc];                 // 4 lanes broadcast-share
    const float lvp   = lv[pc];

    const float* __restrict__ mrow = masses + (size_t)b * L;
    const float* __restrict__ irow = inten  + (size_t)b * L;

    const bool fast = (L == MAXL);   // L=4096: statically unrolled staging

    // ---- stage the whole row: issue all loads first, write LDS after ----
    if (fast) {
        const float4* __restrict__ m4 = reinterpret_cast<const float4*>(mrow);
        const float4* __restrict__ i4 = reinterpret_cast<const float4*>(irow);
        float4 mv0 = m4[t];
        float4 mv1 = m4[t + BLOCK];
        float4 iv0 = i4[t];
        float4 iv1 = i4[t + BLOCK];
        float4* __restrict__ smw = reinterpret_cast<float4*>(sm);
        float4* __restrict__ siw = reinterpret_cast<float4*>(si);
        smw[t]         = mv0;
        smw[t + BLOCK] = mv1;
        siw[t]         = iv0;
        siw[t + BLOCK] = iv1;
    } else {
        for (int i = t; i < L; i += BLOCK) {
            sm[i] = mrow[i];
            si[i] = irow[i];
        }
    }

    const float inv  = __expf(-lvp);           // 1/sigma^2
    const float nh   = -0.5f * inv;
    // arg >= -10  <=>  |d| <= sqrt(20)*sigma; margin covers fp rounding, the
    // exact per-term test below keeps the result bit-for-bit identical.
    const float r    = sqrtf(20.0f / inv) * 1.00001f + 1e-3f;
    const float tlo  = mu_p - r;
    const float thi  = mu_p + r;

    __syncthreads();               // only barrier; no thread returned above

    // ---- split binary search in LDS (no HBM reads at all):
    // even subs: first i with m >= tlo; odd subs: first i with m > thi.
    // 12 uniform iterations for L=4096 -> no trip-count divergence;
    // within a 4-lane group mids coincide pairwise -> LDS broadcast.
    const bool  isHi   = sub & 1;
    const float target = isHi ? thi : tlo;
    int lo = 0, hi = L;
    while (lo < hi) {
        const int   mid = (lo + hi) >> 1;
        const float v   = sm[mid];
        const bool  go  = isHi ? (v <= target) : (v < target);
        if (go) lo = mid + 1; else hi = mid;
    }
    const int other = __shfl_xor(lo, 1);
    const int start = isHi ? other : lo;
    const int end   = isHi ? lo    : other;

    // ---- main loop: ~18 terms per lane from LDS ----
    float acc = 0.0f;
    for (int i = start + sub; i < end; i += SUB) {
        const float d   = sm[i] - mu_p;
        const float arg = d * d * nh;
        if (arg >= THRESH)
            acc += __expf(arg) * si[i];
    }
    acc += __shfl_xor(acc, 1);                 // merge the 4-lane group
    acc += __shfl_xor(acc, 2);
    if (sub == 0 && active)
        out[(size_t)b * N + p] = acc;          // exactly-once '=' write
}

extern "C" void kernel_launch(void* const* d_in, const int* in_sizes, int n_in,
                              void* d_out, int out_size, void* d_ws, size_t ws_size,
                              hipStream_t stream) {
    const float* mu     = (const float*)d_in[0];
    const float* lv     = (const float*)d_in[1];
    const float* masses = (const float*)d_in[2];
    const float* inten  = (const float*)d_in[3];
    float* out = (float*)d_out;

    const int N = in_sizes[0];
    const int B = out_size / N;
    const int L = in_sizes[2] / B;

    const int pgroups = (N + PPB - 1) / PPB;   // 2 for N=256
    dim3 grid(pgroups, B);                     // 256 blocks -> 1 per CU
    peaksense_kernel<<<grid, BLOCK, 0, stream>>>(mu, lv, masses, inten, out, B, L, N);
}

// Round 6
// 64.912 us; speedup vs baseline: 1.2142x; 1.0241x over previous
//
#include <hip/hip_runtime.h>
#include <math.h>

// PeakSense: out[b,p] = sum_i exp(-0.5*(mz[b,i]-mu[p])^2 * exp(-lv[p])) * iv[b,i],
// terms with arg < -10 dropped.
//
// R6 = R5 (measured best, 66.5us) + ONE change: grid transposed to
// (B, pgroups) so the two blocks staging the same row get linear dispatch
// ids b and B+b. With B=128 == 0 mod 8 XCDs, both land on the SAME XCD ->
// the second block's staging reads hit that XCD's L2 (16 rows x 64KB = 1MB
// per XCD << 4MB L2) instead of re-fetching HBM. Kernel HBM fetch ~8.3MB ->
// ~4.5MB. Rationale: post-fill writeback drain degrades the kernel's
// marginal HBM rate to ~0.5-1 TB/s (R4: 33.7MB @ 550GB/s effective), so
// fetched bytes are the dominant remaining cost (R4->R5: -25.6MB = -12.3us).
//
// Structure (unchanged from R5):
//  - 256 blocks (1/CU), BLOCK=512 (8 waves/CU), SUB=4, 128 peaks/block.
//  - float4 issue-early staging, lane-contiguous ds_write_b128, one barrier.
//  - split binary search IN LDS (even subs lower bound, odd subs upper,
//    12 uniform steps for L=4096), shfl_xor(1) exchange.
//  - ~18 main-loop terms per lane from LDS; exact per-term threshold test
//    -> same accumulation set as ref.

#define BLOCK 512
#define SUB 4
#define PPB (BLOCK / SUB)   // 128 peaks per block
#define MAXL 4096
#define THRESH -10.0f

__global__ __launch_bounds__(BLOCK) void peaksense_kernel(
    const float* __restrict__ mu,
    const float* __restrict__ lv,
    const float* __restrict__ masses,
    const float* __restrict__ inten,
    float* __restrict__ out,
    int B, int L, int N)
{
    __shared__ float sm[MAXL];   // masses, 16 KB
    __shared__ float si[MAXL];   // intensities, 16 KB

    const int b  = blockIdx.x;   // row (fast dispatch axis)
    const int pg = blockIdx.y;   // peak group (slow axis -> same-XCD pairs)
    const int t  = threadIdx.x;

    // ---- hoisted peak-parameter loads ----
    const int  lp     = t >> 2;        // local peak 0..127
    const int  sub    = t & 3;         // quarter-range selector
    const int  p      = pg * PPB + lp;
    const bool active = (p < N);
    const int  pc     = active ? p : (N - 1);   // clamp for safe loads
    const float mu_p  = mu[pc];                 // 4 lanes broadcast-share
    const float lvp   = lv[pc];

    const float* __restrict__ mrow = masses + (size_t)b * L;
    const float* __restrict__ irow = inten  + (size_t)b * L;

    const bool fast = (L == MAXL);   // L=4096: statically unrolled staging

    // ---- stage the whole row: issue all loads first, write LDS after ----
    if (fast) {
        const float4* __restrict__ m4 = reinterpret_cast<const float4*>(mrow);
        const float4* __restrict__ i4 = reinterpret_cast<const float4*>(irow);
        float4 mv0 = m4[t];
        float4 mv1 = m4[t + BLOCK];
        float4 iv0 = i4[t];
        float4 iv1 = i4[t + BLOCK];
        float4* __restrict__ smw = reinterpret_cast<float4*>(sm);
        float4* __restrict__ siw = reinterpret_cast<float4*>(si);
        smw[t]         = mv0;
        smw[t + BLOCK] = mv1;
        siw[t]         = iv0;
        siw[t + BLOCK] = iv1;
    } else {
        for (int i = t; i < L; i += BLOCK) {
            sm[i] = mrow[i];
            si[i] = irow[i];
        }
    }

    const float inv  = __expf(-lvp);           // 1/sigma^2
    const float nh   = -0.5f * inv;
    // arg >= -10  <=>  |d| <= sqrt(20)*sigma; margin covers fp rounding, the
    // exact per-term test below keeps the result bit-for-bit identical.
    const float r    = sqrtf(20.0f / inv) * 1.00001f + 1e-3f;
    const float tlo  = mu_p - r;
    const float thi  = mu_p + r;

    __syncthreads();               // only barrier; no thread returned above

    // ---- split binary search in LDS (no HBM reads at all):
    // even subs: first i with m >= tlo; odd subs: first i with m > thi.
    // 12 uniform iterations for L=4096 -> no trip-count divergence;
    // within a 4-lane group mids coincide pairwise -> LDS broadcast.
    const bool  isHi   = sub & 1;
    const float target = isHi ? thi : tlo;
    int lo = 0, hi = L;
    while (lo < hi) {
        const int   mid = (lo + hi) >> 1;
        const float v   = sm[mid];
        const bool  go  = isHi ? (v <= target) : (v < target);
        if (go) lo = mid + 1; else hi = mid;
    }
    const int other = __shfl_xor(lo, 1);
    const int start = isHi ? other : lo;
    const int end   = isHi ? lo    : other;

    // ---- main loop: ~18 terms per lane from LDS ----
    float acc = 0.0f;
    for (int i = start + sub; i < end; i += SUB) {
        const float d   = sm[i] - mu_p;
        const float arg = d * d * nh;
        if (arg >= THRESH)
            acc += __expf(arg) * si[i];
    }
    acc += __shfl_xor(acc, 1);                 // merge the 4-lane group
    acc += __shfl_xor(acc, 2);
    if (sub == 0 && active)
        out[(size_t)b * N + p] = acc;          // exactly-once '=' write
}

extern "C" void kernel_launch(void* const* d_in, const int* in_sizes, int n_in,
                              void* d_out, int out_size, void* d_ws, size_t ws_size,
                              hipStream_t stream) {
    const float* mu     = (const float*)d_in[0];
    const float* lv     = (const float*)d_in[1];
    const float* masses = (const float*)d_in[2];
    const float* inten  = (const float*)d_in[3];
    float* out = (float*)d_out;

    const int N = in_sizes[0];
    const int B = out_size / N;
    const int L = in_sizes[2] / B;

    const int pgroups = (N + PPB - 1) / PPB;   // 2 for N=256
    dim3 grid(B, pgroups);                     // row fast, pg slow -> XCD pairs
    peaksense_kernel<<<grid, BLOCK, 0, stream>>>(mu, lv, masses, inten, out, B, L, N);
}

// Round 7
// 64.127 us; speedup vs baseline: 1.2291x; 1.0122x over previous
//
#include <hip/hip_runtime.h>
#include <math.h>

// PeakSense: out[b,p] = sum_i exp(-0.5*(mz[b,i]-mu[p])^2 * exp(-lv[p])) * iv[b,i],
// terms with arg < -10 dropped.
//
// R7 = R6 (64.9us) + phase-overlap split, fetch-neutral:
//  - 2 blocks/CU (512 blocks of 512 threads = 16 waves/CU): while one
//    block's waves wait on staging-load return or walk the 12-step
//    dependent LDS search, the co-resident block's waves compute (m114:
//    co-scheduled waves overlap fully). R6 had 1 block/CU -> all 8 waves
//    stalled together at the single barrier.
//  - fetch stays ~4.5MB: grid(B, pgroups) gives row b's 4 blocks linear
//    ids b, 128+b, 256+b, 384+b, all == b mod 8 -> same XCD -> one cold
//    HBM fetch + 3 L2 hits (the R4 regression was this ordering done
//    wrong: pairs scattered across XCDs -> 33.7MB HBM).
//  - SUB=8, 64 peaks/block, ~9 main-loop terms per lane.
// Structure otherwise identical to R6: float4 issue-early staging,
// lane-contiguous ds_write_b128, one barrier, split LDS binary search
// (even subs lower bound, odd subs upper, 12 uniform steps), shfl merge,
// exact per-term threshold test -> same accumulation set as ref.

#define BLOCK 512
#define SUB 8
#define PPB (BLOCK / SUB)   // 64 peaks per block
#define MAXL 4096
#define THRESH -10.0f

__global__ __launch_bounds__(BLOCK) void peaksense_kernel(
    const float* __restrict__ mu,
    const float* __restrict__ lv,
    const float* __restrict__ masses,
    const float* __restrict__ inten,
    float* __restrict__ out,
    int B, int L, int N)
{
    __shared__ float sm[MAXL];   // masses, 16 KB
    __shared__ float si[MAXL];   // intensities, 16 KB

    const int b  = blockIdx.x;   // row (fast dispatch axis)
    const int pg = blockIdx.y;   // peak group (slow axis -> same-XCD sets)
    const int t  = threadIdx.x;

    // ---- hoisted peak-parameter loads ----
    const int  lp     = t >> 3;        // local peak 0..63
    const int  sub    = t & 7;         // eighth-range selector
    const int  p      = pg * PPB + lp;
    const bool active = (p < N);
    const int  pc     = active ? p : (N - 1);   // clamp for safe loads
    const float mu_p  = mu[pc];                 // 8 lanes broadcast-share
    const float lvp   = lv[pc];

    const float* __restrict__ mrow = masses + (size_t)b * L;
    const float* __restrict__ irow = inten  + (size_t)b * L;

    const bool fast = (L == MAXL);   // L=4096: statically unrolled staging

    // ---- stage the whole row: issue all loads first, write LDS after ----
    if (fast) {
        const float4* __restrict__ m4 = reinterpret_cast<const float4*>(mrow);
        const float4* __restrict__ i4 = reinterpret_cast<const float4*>(irow);
        float4 mv0 = m4[t];
        float4 mv1 = m4[t + BLOCK];
        float4 iv0 = i4[t];
        float4 iv1 = i4[t + BLOCK];
        float4* __restrict__ smw = reinterpret_cast<float4*>(sm);
        float4* __restrict__ siw = reinterpret_cast<float4*>(si);
        smw[t]         = mv0;
        smw[t + BLOCK] = mv1;
        siw[t]         = iv0;
        siw[t + BLOCK] = iv1;
    } else {
        for (int i = t; i < L; i += BLOCK) {
            sm[i] = mrow[i];
            si[i] = irow[i];
        }
    }

    const float inv  = __expf(-lvp);           // 1/sigma^2
    const float nh   = -0.5f * inv;
    // arg >= -10  <=>  |d| <= sqrt(20)*sigma; margin covers fp rounding, the
    // exact per-term test below keeps the result bit-for-bit identical.
    const float r    = sqrtf(20.0f / inv) * 1.00001f + 1e-3f;
    const float tlo  = mu_p - r;
    const float thi  = mu_p + r;

    __syncthreads();               // only barrier; no thread returned above

    // ---- split binary search in LDS (no HBM reads at all):
    // even subs: first i with m >= tlo; odd subs: first i with m > thi.
    // 12 uniform iterations for L=4096 -> no trip-count divergence;
    // within an 8-lane group mids coincide 4-wise -> LDS broadcast.
    const bool  isHi   = sub & 1;
    const float target = isHi ? thi : tlo;
    int lo = 0, hi = L;
    while (lo < hi) {
        const int   mid = (lo + hi) >> 1;
        const float v   = sm[mid];
        const bool  go  = isHi ? (v <= target) : (v < target);
        if (go) lo = mid + 1; else hi = mid;
    }
    const int other = __shfl_xor(lo, 1);
    const int start = isHi ? other : lo;
    const int end   = isHi ? lo    : other;

    // ---- main loop: ~9 terms per lane from LDS ----
    float acc = 0.0f;
    for (int i = start + sub; i < end; i += SUB) {
        const float d   = sm[i] - mu_p;
        const float arg = d * d * nh;
        if (arg >= THRESH)
            acc += __expf(arg) * si[i];
    }
    acc += __shfl_xor(acc, 1);                 // merge the 8-lane group
    acc += __shfl_xor(acc, 2);
    acc += __shfl_xor(acc, 4);
    if (sub == 0 && active)
        out[(size_t)b * N + p] = acc;          // exactly-once '=' write
}

extern "C" void kernel_launch(void* const* d_in, const int* in_sizes, int n_in,
                              void* d_out, int out_size, void* d_ws, size_t ws_size,
                              hipStream_t stream) {
    const float* mu     = (const float*)d_in[0];
    const float* lv     = (const float*)d_in[1];
    const float* masses = (const float*)d_in[2];
    const float* inten  = (const float*)d_in[3];
    float* out = (float*)d_out;

    const int N = in_sizes[0];
    const int B = out_size / N;
    const int L = in_sizes[2] / B;

    const int pgroups = (N + PPB - 1) / PPB;   // 4 for N=256
    dim3 grid(B, pgroups);                     // row fast -> same-XCD sets
    peaksense_kernel<<<grid, BLOCK, 0, stream>>>(mu, lv, masses, inten, out, B, L, N);
}